// Round 2
// baseline (3326.504 us; speedup 1.0000x reference)
//
#include <hip/hip_runtime.h>
#include <stdint.h>

// AmbientSphericalBrownianMotion: 100 Stratonovich-Heun steps of spherical BM.
// RNG replicates modern JAX (jax_threefry_partitionable=True, default since
// 0.4.36): bits[j] = w0 ^ w1 of threefry2x32(step_key, (hi=0, lo=j)), where
// step_key = fold_in(key(1), i) = threefry2x32((0,1), (0,i)).
// One thread per point; whole 100-step trajectory lives in registers.
// HBM traffic: one 48 MB read + one 48 MB write. Expected VALU-bound.

#define BLOCK 256

struct V3 { float x, y, z; };

__device__ __forceinline__ void tf_round(uint32_t& x0, uint32_t& x1, int r) {
    x0 += x1;
    x1 = (x1 << r) | (x1 >> (32 - r));   // -> v_alignbit_b32
    x1 ^= x0;
}

// JAX / Random123 Threefry-2x32, 20 rounds.
__device__ __forceinline__ uint2 threefry2x32(uint32_t k0, uint32_t k1,
                                              uint32_t x0, uint32_t x1) {
    uint32_t k2 = k0 ^ k1 ^ 0x1BD11BDAu;
    x0 += k0; x1 += k1;
    tf_round(x0,x1,13); tf_round(x0,x1,15); tf_round(x0,x1,26); tf_round(x0,x1,6);
    x0 += k1; x1 += k2 + 1u;
    tf_round(x0,x1,17); tf_round(x0,x1,29); tf_round(x0,x1,16); tf_round(x0,x1,24);
    x0 += k2; x1 += k0 + 2u;
    tf_round(x0,x1,13); tf_round(x0,x1,15); tf_round(x0,x1,26); tf_round(x0,x1,6);
    x0 += k0; x1 += k1 + 3u;
    tf_round(x0,x1,17); tf_round(x0,x1,29); tf_round(x0,x1,16); tf_round(x0,x1,24);
    x0 += k1; x1 += k2 + 4u;
    tf_round(x0,x1,13); tf_round(x0,x1,15); tf_round(x0,x1,26); tf_round(x0,x1,6);
    x0 += k2; x1 += k0 + 5u;
    return make_uint2(x0, x1);
}

// Partitionable random_bits for 32-bit output: xor of the two output words,
// counter = (hi, lo) of the 64-bit flat element index (hi == 0 here).
__device__ __forceinline__ uint32_t tf_bits(uint32_t k0, uint32_t k1, uint32_t j) {
    uint2 h = threefry2x32(k0, k1, 0u, j);
    return h.x ^ h.y;
}

// XLA ErfInv32 (Giles): w = -log1p(-x*x); two 9-term polys, select at w<5.
__device__ __forceinline__ float erfinv_f32(float x) {
    float s  = x * x;
    float tt = 1.0f - s;       // exact in the tail (Sterbenz), matches log1p path
    float w  = -__logf(tt);
    float wa = w - 2.5f;
    float wb = __builtin_amdgcn_sqrtf(w) - 3.0f;
    float pa =  2.81022636e-08f;
    pa = fmaf(pa, wa,  3.43273939e-07f);
    pa = fmaf(pa, wa, -3.5233877e-06f);
    pa = fmaf(pa, wa, -4.39150654e-06f);
    pa = fmaf(pa, wa,  0.00021858087f);
    pa = fmaf(pa, wa, -0.00125372503f);
    pa = fmaf(pa, wa, -0.00417768164f);
    pa = fmaf(pa, wa,  0.246640727f);
    pa = fmaf(pa, wa,  1.50140941f);
    float pb = -0.000200214257f;
    pb = fmaf(pb, wb,  0.000100950558f);
    pb = fmaf(pb, wb,  0.00134934322f);
    pb = fmaf(pb, wb, -0.00367342844f);
    pb = fmaf(pb, wb,  0.00573950773f);
    pb = fmaf(pb, wb, -0.0076224613f);
    pb = fmaf(pb, wb,  0.00943887047f);
    pb = fmaf(pb, wb,  1.00167406f);
    pb = fmaf(pb, wb,  2.83297682f);
    float p = (w < 5.0f) ? pa : pb;
    return p * x;
}

// JAX normal(): u = max(mn, u01*2 + mn), mn = nextafter(-1,0); z = sqrt(2)*erfinv(u).
__device__ __forceinline__ float bits_to_normal(uint32_t bits) {
    const float mn = -0.99999994f;                                  // 0xBF7FFFFF
    float u01 = __uint_as_float((bits >> 9) | 0x3f800000u) - 1.0f;  // [0,1)
    float u   = fmaf(u01, 2.0f, mn);    // (maxval-minval) rounds to 2.0f exactly
    u = fmaxf(u, mn);
    return 1.41421356237f * erfinv_f32(u);
}

__device__ __forceinline__ float rcp_f(float a) { return __builtin_amdgcn_rcpf(a); }

__device__ __forceinline__ void heun_step(V3& p, V3 inc) {
    // g0 = proj2tangent(x, inc)
    float d  = p.x*inc.x + p.y*inc.y + p.z*inc.z;
    float n2 = p.x*p.x + p.y*p.y + p.z*p.z;
    float q  = d * rcp_f(n2);
    V3 g0 = { inc.x - q*p.x, inc.y - q*p.y, inc.z - q*p.z };
    // y' = x + g0 ; g' = proj2tangent(y', inc)
    V3 yp = { p.x + g0.x, p.y + g0.y, p.z + g0.z };
    float d2 = yp.x*inc.x + yp.y*inc.y + yp.z*inc.z;
    float m2 = yp.x*yp.x + yp.y*yp.y + yp.z*yp.z;
    float q2 = d2 * rcp_f(m2);
    V3 gp = { inc.x - q2*yp.x, inc.y - q2*yp.y, inc.z - q2*yp.z };
    // y1 = x + 0.5*(g0+g') ; x = y1/||y1||
    V3 y1 = { p.x + 0.5f*(g0.x+gp.x), p.y + 0.5f*(g0.y+gp.y), p.z + 0.5f*(g0.z+gp.z) };
    float r2   = y1.x*y1.x + y1.y*y1.y + y1.z*y1.z;
    float rinv = __builtin_amdgcn_rsqf(r2);
    p.x = y1.x * rinv; p.y = y1.y * rinv; p.z = y1.z * rinv;
}

__global__ __launch_bounds__(BLOCK)
void sbm_kernel(const float* __restrict__ xin,
                const int* __restrict__ t_ptr,
                const int* __restrict__ steps_ptr,
                float* __restrict__ out,
                uint32_t npts) {
    __shared__ uint2 skeys[128];

    const int steps = steps_ptr[0];
    const int tval  = t_ptr[0];
    const int tid   = threadIdx.x;

    // Per-step keys: fold_in(key(1), i) = threefry2x32((0,1), (0,i)).
    if (tid < steps && tid < 128) skeys[tid] = threefry2x32(0u, 1u, 0u, (uint32_t)tid);
    __syncthreads();

    const float dt  = (float)((double)tval / (double)steps);  // f32(t/steps)
    const float sdt = sqrtf(dt);

    const uint32_t g = blockIdx.x * BLOCK + tid;
    if (g >= npts) return;

    const float* px = xin + 3u * g;
    V3 P = { px[0], px[1], px[2] };
    const uint32_t j0 = 3u * g;   // flat element index of this point's row

    for (int i = 0; i < steps; ++i) {
        uint2 key = skeys[i & 127];
        uint32_t b0 = tf_bits(key.x, key.y, j0);
        uint32_t b1 = tf_bits(key.x, key.y, j0 + 1u);
        uint32_t b2 = tf_bits(key.x, key.y, j0 + 2u);
        V3 inc = { bits_to_normal(b0) * sdt,
                   bits_to_normal(b1) * sdt,
                   bits_to_normal(b2) * sdt };
        heun_step(P, inc);
    }

    float* po = out + 3u * g;
    po[0] = P.x; po[1] = P.y; po[2] = P.z;
}

extern "C" void kernel_launch(void* const* d_in, const int* in_sizes, int n_in,
                              void* d_out, int out_size, void* d_ws, size_t ws_size,
                              hipStream_t stream) {
    const float* x      = (const float*)d_in[0];
    const int*   t_ptr  = (const int*)d_in[1];
    const int*   steps  = (const int*)d_in[2];
    float*       out    = (float*)d_out;

    const uint32_t npts = (uint32_t)(in_sizes[0] / 3);     // 4194304 points
    const uint32_t grid = (npts + BLOCK - 1) / BLOCK;      // 16384 blocks

    sbm_kernel<<<grid, BLOCK, 0, stream>>>(x, t_ptr, steps, out, npts);
}

// Round 3
// 2836.399 us; speedup vs baseline: 1.1728x; 1.1728x over previous
//
#include <hip/hip_runtime.h>
#include <stdint.h>

// AmbientSphericalBrownianMotion: 100 Stratonovich-Heun steps of spherical BM.
// RNG replicates modern JAX (jax_threefry_partitionable=True): bits[j] =
// w0 ^ w1 of threefry2x32(step_key, (0, j)); step_key = fold_in(key(1), i).
// Pure VALU-bound (measured ceiling ~103 TF fma-rate). Round-3 changes:
//  - tail poly (w>=5, 0.34%/sample) moved behind a wave-uniform __any branch
//  - redundant fmaxf(u, mn) removed (fma(u01,2,mn) >= mn provably)
//  - sqrt(2)*sdt folded into one scalar multiplier
// Keeping 1-u*u (NOT fma) for bit-exact tail w; keeping LDS step-key table.

#define BLOCK 256

struct V3 { float x, y, z; };

__device__ __forceinline__ void tf_round(uint32_t& x0, uint32_t& x1, int r) {
    x0 += x1;
    x1 = (x1 << r) | (x1 >> (32 - r));   // -> v_alignbit_b32
    x1 ^= x0;
}

// JAX / Random123 Threefry-2x32, 20 rounds.
__device__ __forceinline__ uint2 threefry2x32(uint32_t k0, uint32_t k1,
                                              uint32_t x0, uint32_t x1) {
    uint32_t k2 = k0 ^ k1 ^ 0x1BD11BDAu;
    x0 += k0; x1 += k1;
    tf_round(x0,x1,13); tf_round(x0,x1,15); tf_round(x0,x1,26); tf_round(x0,x1,6);
    x0 += k1; x1 += k2 + 1u;
    tf_round(x0,x1,17); tf_round(x0,x1,29); tf_round(x0,x1,16); tf_round(x0,x1,24);
    x0 += k2; x1 += k0 + 2u;
    tf_round(x0,x1,13); tf_round(x0,x1,15); tf_round(x0,x1,26); tf_round(x0,x1,6);
    x0 += k0; x1 += k1 + 3u;
    tf_round(x0,x1,17); tf_round(x0,x1,29); tf_round(x0,x1,16); tf_round(x0,x1,24);
    x0 += k1; x1 += k2 + 4u;
    tf_round(x0,x1,13); tf_round(x0,x1,15); tf_round(x0,x1,26); tf_round(x0,x1,6);
    x0 += k2; x1 += k0 + 5u;
    return make_uint2(x0, x1);
}

// Partitionable random_bits (32-bit): xor of both output words, counter (0, j).
__device__ __forceinline__ uint32_t tf_bits(uint32_t k0, uint32_t k1, uint32_t j) {
    uint2 h = threefry2x32(k0, k1, 0u, j);
    return h.x ^ h.y;
}

// bits -> increment = sqrt(2)*erfinv(u)*sdt, with c = sqrt2*sdt prefolded.
// XLA ErfInv32 (Giles); tail poly behind a wave-uniform branch.
__device__ __forceinline__ float bits_to_inc(uint32_t bits, float c) {
    const float mn = -0.99999994f;                                  // 0xBF7FFFFF
    float u01 = __uint_as_float((bits >> 9) | 0x3f800000u) - 1.0f;  // [0,1)
    float u   = fmaf(u01, 2.0f, mn);      // >= mn always; fmax redundant
    float s   = u * u;
    float tt  = 1.0f - s;                 // Sterbenz-exact in tail; matches XLA -(x*x)
    float w   = -__logf(tt);
    float wa  = w - 2.5f;
    float p =  2.81022636e-08f;
    p = fmaf(p, wa,  3.43273939e-07f);
    p = fmaf(p, wa, -3.5233877e-06f);
    p = fmaf(p, wa, -4.39150654e-06f);
    p = fmaf(p, wa,  0.00021858087f);
    p = fmaf(p, wa, -0.00125372503f);
    p = fmaf(p, wa, -0.00417768164f);
    p = fmaf(p, wa,  0.246640727f);
    p = fmaf(p, wa,  1.50140941f);
    if (__builtin_expect(__any(w >= 5.0f), 0)) {   // ~20%/wave/sample
        float wb = __builtin_amdgcn_sqrtf(w) - 3.0f;
        float q = -0.000200214257f;
        q = fmaf(q, wb,  0.000100950558f);
        q = fmaf(q, wb,  0.00134934322f);
        q = fmaf(q, wb, -0.00367342844f);
        q = fmaf(q, wb,  0.00573950773f);
        q = fmaf(q, wb, -0.0076224613f);
        q = fmaf(q, wb,  0.00943887047f);
        q = fmaf(q, wb,  1.00167406f);
        q = fmaf(q, wb,  2.83297682f);
        p = (w < 5.0f) ? p : q;
    }
    return (p * u) * c;
}

__device__ __forceinline__ float rcp_f(float a) { return __builtin_amdgcn_rcpf(a); }

__device__ __forceinline__ void heun_step(V3& p, V3 inc) {
    float d  = p.x*inc.x + p.y*inc.y + p.z*inc.z;
    float n2 = p.x*p.x + p.y*p.y + p.z*p.z;
    float q  = d * rcp_f(n2);
    V3 g0 = { inc.x - q*p.x, inc.y - q*p.y, inc.z - q*p.z };
    V3 yp = { p.x + g0.x, p.y + g0.y, p.z + g0.z };
    float d2 = yp.x*inc.x + yp.y*inc.y + yp.z*inc.z;
    float m2 = yp.x*yp.x + yp.y*yp.y + yp.z*yp.z;
    float q2 = d2 * rcp_f(m2);
    V3 gp = { inc.x - q2*yp.x, inc.y - q2*yp.y, inc.z - q2*yp.z };
    V3 y1 = { p.x + 0.5f*(g0.x+gp.x), p.y + 0.5f*(g0.y+gp.y), p.z + 0.5f*(g0.z+gp.z) };
    float r2   = y1.x*y1.x + y1.y*y1.y + y1.z*y1.z;
    float rinv = __builtin_amdgcn_rsqf(r2);
    p.x = y1.x * rinv; p.y = y1.y * rinv; p.z = y1.z * rinv;
}

__global__ __launch_bounds__(BLOCK)
void sbm_kernel(const float* __restrict__ xin,
                const int* __restrict__ t_ptr,
                const int* __restrict__ steps_ptr,
                float* __restrict__ out,
                uint32_t npts) {
    __shared__ uint2 skeys[128];

    const int steps = steps_ptr[0];
    const int tval  = t_ptr[0];
    const int tid   = threadIdx.x;

    // Per-step keys: fold_in(key(1), i) = threefry2x32((0,1), (0,i)).
    if (tid < steps && tid < 128) skeys[tid] = threefry2x32(0u, 1u, 0u, (uint32_t)tid);
    __syncthreads();

    const float dt  = (float)((double)tval / (double)steps);  // f32(t/steps)
    const float sdt = sqrtf(dt);
    const float c   = 1.41421356237f * sdt;   // sqrt2 * sdt prefolded

    const uint32_t g = blockIdx.x * BLOCK + tid;
    if (g >= npts) return;

    const float* px = xin + 3u * g;
    V3 P = { px[0], px[1], px[2] };
    const uint32_t j0 = 3u * g;

    for (int i = 0; i < steps; ++i) {
        uint2 key = skeys[i & 127];
        uint32_t b0 = tf_bits(key.x, key.y, j0);
        uint32_t b1 = tf_bits(key.x, key.y, j0 + 1u);
        uint32_t b2 = tf_bits(key.x, key.y, j0 + 2u);
        V3 inc = { bits_to_inc(b0, c), bits_to_inc(b1, c), bits_to_inc(b2, c) };
        heun_step(P, inc);
    }

    float* po = out + 3u * g;
    po[0] = P.x; po[1] = P.y; po[2] = P.z;
}

extern "C" void kernel_launch(void* const* d_in, const int* in_sizes, int n_in,
                              void* d_out, int out_size, void* d_ws, size_t ws_size,
                              hipStream_t stream) {
    const float* x      = (const float*)d_in[0];
    const int*   t_ptr  = (const int*)d_in[1];
    const int*   steps  = (const int*)d_in[2];
    float*       out    = (float*)d_out;

    const uint32_t npts = (uint32_t)(in_sizes[0] / 3);     // 4194304 points
    const uint32_t grid = (npts + BLOCK - 1) / BLOCK;      // 16384 blocks

    sbm_kernel<<<grid, BLOCK, 0, stream>>>(x, t_ptr, steps, out, npts);
}

// Round 4
// 2706.242 us; speedup vs baseline: 1.2292x; 1.0481x over previous
//
#include <hip/hip_runtime.h>
#include <stdint.h>

// AmbientSphericalBrownianMotion: 100 Stratonovich-Heun steps of spherical BM.
// RNG = modern JAX (jax_threefry_partitionable=True): bits[j] = w0^w1 of
// threefry2x32(step_key, (0,j)); step_key = fold_in(key(1), i).
// VALU-issue-bound at ~91% of the measured ceiling (m07: ~5.15e13 lane-ops/s).
// Round-4 changes:
//  - 2 points/thread (g, g+N/2): ILP to hide log/rcp/LDS latency
//  - step keys readfirstlane'd to SGPRs -> Threefry key schedule on SALU
//  - first tangent projection uses |x|^2 == 1 (renormalized every step)
//  - raw log2 with -ln2 folded into the poly shift; tail test on lg directly

#define BLOCK 256

struct V3 { float x, y, z; };

__device__ __forceinline__ void tf_round(uint32_t& x0, uint32_t& x1, int r) {
    x0 += x1;
    x1 = (x1 << r) | (x1 >> (32 - r));   // -> v_alignbit_b32
    x1 ^= x0;
}

// JAX / Random123 Threefry-2x32, 20 rounds. k0,k1 are wave-uniform SGPRs
// in the hot loop, so the key schedule is SALU.
__device__ __forceinline__ uint2 threefry2x32(uint32_t k0, uint32_t k1,
                                              uint32_t x0, uint32_t x1) {
    uint32_t k2 = k0 ^ k1 ^ 0x1BD11BDAu;
    x0 += k0; x1 += k1;
    tf_round(x0,x1,13); tf_round(x0,x1,15); tf_round(x0,x1,26); tf_round(x0,x1,6);
    x0 += k1; x1 += k2 + 1u;
    tf_round(x0,x1,17); tf_round(x0,x1,29); tf_round(x0,x1,16); tf_round(x0,x1,24);
    x0 += k2; x1 += k0 + 2u;
    tf_round(x0,x1,13); tf_round(x0,x1,15); tf_round(x0,x1,26); tf_round(x0,x1,6);
    x0 += k0; x1 += k1 + 3u;
    tf_round(x0,x1,17); tf_round(x0,x1,29); tf_round(x0,x1,16); tf_round(x0,x1,24);
    x0 += k1; x1 += k2 + 4u;
    tf_round(x0,x1,13); tf_round(x0,x1,15); tf_round(x0,x1,26); tf_round(x0,x1,6);
    x0 += k2; x1 += k0 + 5u;
    return make_uint2(x0, x1);
}

// Partitionable random_bits (32-bit): xor of both output words, counter (0, j).
__device__ __forceinline__ uint32_t tf_bits(uint32_t k0, uint32_t k1, uint32_t j) {
    uint2 h = threefry2x32(k0, k1, 0u, j);
    return h.x ^ h.y;
}

// bits -> increment = sqrt(2)*erfinv(u)*sdt with c = sqrt2*sdt prefolded.
// XLA ErfInv32 (Giles). lg = log2(tt); w = -ln2*lg folded into wa.
// Tail (w>=5 <=> lg <= -5/ln2, 0.34%/sample) behind a wave-uniform branch.
__device__ __forceinline__ float bits_to_inc(uint32_t bits, float c) {
    const float mn = -0.99999994f;                                  // 0xBF7FFFFF
    float u01 = __uint_as_float((bits >> 9) | 0x3f800000u) - 1.0f;  // [0,1)
    float u   = fmaf(u01, 2.0f, mn);      // >= mn always; fmax provably redundant
    float s   = u * u;
    float tt  = 1.0f - s;                 // Sterbenz-exact in tail
    float lg  = __log2f(tt);              // v_log_f32
    const float nln2 = -0.69314718f;
    float wa  = fmaf(lg, nln2, -2.5f);    // w - 2.5
    float p =  2.81022636e-08f;
    p = fmaf(p, wa,  3.43273939e-07f);
    p = fmaf(p, wa, -3.5233877e-06f);
    p = fmaf(p, wa, -4.39150654e-06f);
    p = fmaf(p, wa,  0.00021858087f);
    p = fmaf(p, wa, -0.00125372503f);
    p = fmaf(p, wa, -0.00417768164f);
    p = fmaf(p, wa,  0.246640727f);
    p = fmaf(p, wa,  1.50140941f);
    if (__builtin_expect(__any(lg <= -7.2134752f), 0)) {   // w >= 5
        float w  = lg * nln2;
        float wb = __builtin_amdgcn_sqrtf(w) - 3.0f;
        float q = -0.000200214257f;
        q = fmaf(q, wb,  0.000100950558f);
        q = fmaf(q, wb,  0.00134934322f);
        q = fmaf(q, wb, -0.00367342844f);
        q = fmaf(q, wb,  0.00573950773f);
        q = fmaf(q, wb, -0.0076224613f);
        q = fmaf(q, wb,  0.00943887047f);
        q = fmaf(q, wb,  1.00167406f);
        q = fmaf(q, wb,  2.83297682f);
        p = (lg > -7.2134752f) ? p : q;
    }
    return (p * u) * c;
}

__device__ __forceinline__ float rcp_f(float a) { return __builtin_amdgcn_rcpf(a); }

// |p| == 1 on entry (renormalized every step; setup_inputs also normalizes),
// so the first projection's dot/nrm2 divide is skipped: |p|^2 = 1 +- 2ulp,
// perturbation ~2e-8/step — same order as existing rounding noise.
__device__ __forceinline__ void heun_step(V3& p, V3 inc) {
    float d  = p.x*inc.x + p.y*inc.y + p.z*inc.z;
    V3 g0 = { inc.x - d*p.x, inc.y - d*p.y, inc.z - d*p.z };
    V3 yp = { p.x + g0.x, p.y + g0.y, p.z + g0.z };
    float d2 = yp.x*inc.x + yp.y*inc.y + yp.z*inc.z;
    float m2 = yp.x*yp.x + yp.y*yp.y + yp.z*yp.z;
    float q2 = d2 * rcp_f(m2);
    V3 gp = { inc.x - q2*yp.x, inc.y - q2*yp.y, inc.z - q2*yp.z };
    V3 y1 = { p.x + 0.5f*(g0.x+gp.x), p.y + 0.5f*(g0.y+gp.y), p.z + 0.5f*(g0.z+gp.z) };
    float r2   = y1.x*y1.x + y1.y*y1.y + y1.z*y1.z;
    float rinv = __builtin_amdgcn_rsqf(r2);
    p.x = y1.x * rinv; p.y = y1.y * rinv; p.z = y1.z * rinv;
}

__global__ __launch_bounds__(BLOCK)
void sbm_kernel(const float* __restrict__ xin,
                const int* __restrict__ t_ptr,
                const int* __restrict__ steps_ptr,
                float* __restrict__ out,
                uint32_t nhalf) {
    __shared__ uint2 skeys[128];

    const int steps = steps_ptr[0];
    const int tval  = t_ptr[0];
    const int tid   = threadIdx.x;

    // Per-step keys: fold_in(key(1), i) = threefry2x32((0,1), (0,i)).
    if (tid < steps && tid < 128) skeys[tid] = threefry2x32(0u, 1u, 0u, (uint32_t)tid);
    __syncthreads();

    const float dt  = (float)((double)tval / (double)steps);  // f32(t/steps)
    const float sdt = sqrtf(dt);
    const float c   = 1.41421356237f * sdt;   // sqrt2 * sdt prefolded

    const uint32_t g = blockIdx.x * BLOCK + tid;
    if (g >= nhalf) return;

    const float* pa = xin + 3u * g;
    const float* pb = xin + 3u * (g + nhalf);
    V3 A = { pa[0], pa[1], pa[2] };
    V3 B = { pb[0], pb[1], pb[2] };
    const uint32_t ja = 3u * g;
    const uint32_t jb = 3u * (g + nhalf);

    for (int i = 0; i < steps; ++i) {
        uint2 key = skeys[i & 127];
        uint32_t k0 = __builtin_amdgcn_readfirstlane(key.x);  // SGPR keys ->
        uint32_t k1 = __builtin_amdgcn_readfirstlane(key.y);  // SALU key schedule
        uint32_t a0 = tf_bits(k0, k1, ja);
        uint32_t a1 = tf_bits(k0, k1, ja + 1u);
        uint32_t a2 = tf_bits(k0, k1, ja + 2u);
        uint32_t b0 = tf_bits(k0, k1, jb);
        uint32_t b1 = tf_bits(k0, k1, jb + 1u);
        uint32_t b2 = tf_bits(k0, k1, jb + 2u);
        V3 incA = { bits_to_inc(a0, c), bits_to_inc(a1, c), bits_to_inc(a2, c) };
        V3 incB = { bits_to_inc(b0, c), bits_to_inc(b1, c), bits_to_inc(b2, c) };
        heun_step(A, incA);
        heun_step(B, incB);
    }

    float* oa = out + 3u * g;
    float* ob = out + 3u * (g + nhalf);
    oa[0] = A.x; oa[1] = A.y; oa[2] = A.z;
    ob[0] = B.x; ob[1] = B.y; ob[2] = B.z;
}

extern "C" void kernel_launch(void* const* d_in, const int* in_sizes, int n_in,
                              void* d_out, int out_size, void* d_ws, size_t ws_size,
                              hipStream_t stream) {
    const float* x      = (const float*)d_in[0];
    const int*   t_ptr  = (const int*)d_in[1];
    const int*   steps  = (const int*)d_in[2];
    float*       out    = (float*)d_out;

    const uint32_t npts  = (uint32_t)(in_sizes[0] / 3);    // 4194304 points
    const uint32_t nhalf = npts / 2;                       // 2097152 threads
    const uint32_t grid  = (nhalf + BLOCK - 1) / BLOCK;    // 8192 blocks

    sbm_kernel<<<grid, BLOCK, 0, stream>>>(x, t_ptr, steps, out, nhalf);
}

// Round 5
// 2642.492 us; speedup vs baseline: 1.2589x; 1.0241x over previous
//
#include <hip/hip_runtime.h>
#include <stdint.h>

// AmbientSphericalBrownianMotion: 100 Stratonovich-Heun steps of spherical BM.
// RNG = modern JAX (jax_threefry_partitionable=True): bits[j] = w0^w1 of
// threefry2x32(step_key, (0,j)); step_key = fold_in(key(1), i).
// VALU-issue-bound; threefry (213 of ~300 lane-ops/point/step) is
// bit-exactness-locked. Round-5 changes (op shave only):
//  - Heun algebra: yh = (p+inc) + (1-q2)*yp, 2x factor cancels in normalize
//  - sqrt2*sdt folded into the 9 erfinv Horner coefficients (exact c*p)
//  - tail predicate on tt (= e^-5 boundary) -> v_cmp independent of v_log

#define BLOCK 256

struct V3 { float x, y, z; };

__device__ __forceinline__ void tf_round(uint32_t& x0, uint32_t& x1, int r) {
    x0 += x1;
    x1 = (x1 << r) | (x1 >> (32 - r));   // -> v_alignbit_b32
    x1 ^= x0;
}

// JAX / Random123 Threefry-2x32, 20 rounds. k0,k1 wave-uniform (SGPR) in the
// hot loop -> key schedule on SALU, keys fold in as SGPR operands.
__device__ __forceinline__ uint2 threefry2x32(uint32_t k0, uint32_t k1,
                                              uint32_t x0, uint32_t x1) {
    uint32_t k2 = k0 ^ k1 ^ 0x1BD11BDAu;
    x0 += k0; x1 += k1;
    tf_round(x0,x1,13); tf_round(x0,x1,15); tf_round(x0,x1,26); tf_round(x0,x1,6);
    x0 += k1; x1 += k2 + 1u;
    tf_round(x0,x1,17); tf_round(x0,x1,29); tf_round(x0,x1,16); tf_round(x0,x1,24);
    x0 += k2; x1 += k0 + 2u;
    tf_round(x0,x1,13); tf_round(x0,x1,15); tf_round(x0,x1,26); tf_round(x0,x1,6);
    x0 += k0; x1 += k1 + 3u;
    tf_round(x0,x1,17); tf_round(x0,x1,29); tf_round(x0,x1,16); tf_round(x0,x1,24);
    x0 += k1; x1 += k2 + 4u;
    tf_round(x0,x1,13); tf_round(x0,x1,15); tf_round(x0,x1,26); tf_round(x0,x1,6);
    x0 += k2; x1 += k0 + 5u;
    return make_uint2(x0, x1);
}

// Partitionable random_bits (32-bit): xor of both output words, counter (0, j).
__device__ __forceinline__ uint32_t tf_bits(uint32_t k0, uint32_t k1, uint32_t j) {
    uint2 h = threefry2x32(k0, k1, 0u, j);
    return h.x ^ h.y;
}

struct Coef { float a[9]; };

// bits -> increment = sqrt(2)*erfinv(u)*sdt; the scale c is prefolded into
// the primary Horner coefficients (C.a[i] = c * orig[i], giving exactly c*p).
// Tail: w>=5 <=> tt <= e^-5; 0.34%/sample, wave-uniform branch.
__device__ __forceinline__ float bits_to_inc(uint32_t bits, const Coef& C, float c) {
    const float mn   = -0.99999994f;                                // 0xBF7FFFFF
    const float eTm5 =  6.7379470e-3f;                              // e^-5
    float u01 = __uint_as_float((bits >> 9) | 0x3f800000u) - 1.0f;  // [0,1)
    float u   = fmaf(u01, 2.0f, mn);      // >= mn always; fmax provably redundant
    float s   = u * u;
    float tt  = 1.0f - s;                 // Sterbenz-exact in tail
    float lg  = __log2f(tt);              // v_log_f32
    const float nln2 = -0.69314718f;
    float wa  = fmaf(lg, nln2, -2.5f);    // w - 2.5
    float p = C.a[0];
    p = fmaf(p, wa, C.a[1]);
    p = fmaf(p, wa, C.a[2]);
    p = fmaf(p, wa, C.a[3]);
    p = fmaf(p, wa, C.a[4]);
    p = fmaf(p, wa, C.a[5]);
    p = fmaf(p, wa, C.a[6]);
    p = fmaf(p, wa, C.a[7]);
    p = fmaf(p, wa, C.a[8]);              // == c * poly_a(wa)
    if (__builtin_expect(__any(tt <= eTm5), 0)) {
        float w  = lg * nln2;
        float wb = __builtin_amdgcn_sqrtf(w) - 3.0f;
        float q = -0.000200214257f;
        q = fmaf(q, wb,  0.000100950558f);
        q = fmaf(q, wb,  0.00134934322f);
        q = fmaf(q, wb, -0.00367342844f);
        q = fmaf(q, wb,  0.00573950773f);
        q = fmaf(q, wb, -0.0076224613f);
        q = fmaf(q, wb,  0.00943887047f);
        q = fmaf(q, wb,  1.00167406f);
        q = fmaf(q, wb,  2.83297682f);
        q = q * c;
        p = (tt > eTm5) ? p : q;
    }
    return p * u;
}

__device__ __forceinline__ float rcp_f(float a) { return __builtin_amdgcn_rcpf(a); }

// |p| == 1 on entry (renormalized every step). Algebra:
//   yp = p + inc - d*p = pi - d*p        (pi = p + inc)
//   2*y1 = p + inc + (1-q2)*yp = pi + t*yp
//   normalize kills the factor 2 exactly.
__device__ __forceinline__ void heun_step(V3& p, V3 inc) {
    float d  = p.x*inc.x + p.y*inc.y + p.z*inc.z;
    V3 pi = { p.x + inc.x, p.y + inc.y, p.z + inc.z };
    V3 yp = { pi.x - d*p.x, pi.y - d*p.y, pi.z - d*p.z };
    float d2 = yp.x*inc.x + yp.y*inc.y + yp.z*inc.z;
    float m2 = yp.x*yp.x + yp.y*yp.y + yp.z*yp.z;
    float q2 = d2 * rcp_f(m2);
    float t  = 1.0f - q2;
    V3 yh = { pi.x + t*yp.x, pi.y + t*yp.y, pi.z + t*yp.z };   // = 2*y1
    float r2   = yh.x*yh.x + yh.y*yh.y + yh.z*yh.z;
    float rinv = __builtin_amdgcn_rsqf(r2);
    p.x = yh.x * rinv; p.y = yh.y * rinv; p.z = yh.z * rinv;
}

__global__ __launch_bounds__(BLOCK)
void sbm_kernel(const float* __restrict__ xin,
                const int* __restrict__ t_ptr,
                const int* __restrict__ steps_ptr,
                float* __restrict__ out,
                uint32_t nhalf) {
    __shared__ uint2 skeys[128];

    const int steps = steps_ptr[0];
    const int tval  = t_ptr[0];
    const int tid   = threadIdx.x;

    // Per-step keys: fold_in(key(1), i) = threefry2x32((0,1), (0,i)).
    if (tid < steps && tid < 128) skeys[tid] = threefry2x32(0u, 1u, 0u, (uint32_t)tid);
    __syncthreads();

    const float dt  = (float)((double)tval / (double)steps);  // f32(t/steps)
    const float sdt = sqrtf(dt);
    const float c   = 1.41421356237f * sdt;   // sqrt2 * sdt

    // c-scaled primary-branch Horner coefficients (exactly c*poly by induction)
    Coef C;
    C.a[0] = c *  2.81022636e-08f;
    C.a[1] = c *  3.43273939e-07f;
    C.a[2] = c * -3.5233877e-06f;
    C.a[3] = c * -4.39150654e-06f;
    C.a[4] = c *  0.00021858087f;
    C.a[5] = c * -0.00125372503f;
    C.a[6] = c * -0.00417768164f;
    C.a[7] = c *  0.246640727f;
    C.a[8] = c *  1.50140941f;

    const uint32_t g = blockIdx.x * BLOCK + tid;
    if (g >= nhalf) return;

    const float* pa = xin + 3u * g;
    const float* pb = xin + 3u * (g + nhalf);
    V3 A = { pa[0], pa[1], pa[2] };
    V3 B = { pb[0], pb[1], pb[2] };
    const uint32_t ja = 3u * g;
    const uint32_t jb = 3u * (g + nhalf);

    for (int i = 0; i < steps; ++i) {
        uint2 key = skeys[i & 127];
        uint32_t k0 = __builtin_amdgcn_readfirstlane(key.x);
        uint32_t k1 = __builtin_amdgcn_readfirstlane(key.y);
        uint32_t a0 = tf_bits(k0, k1, ja);
        uint32_t a1 = tf_bits(k0, k1, ja + 1u);
        uint32_t a2 = tf_bits(k0, k1, ja + 2u);
        uint32_t b0 = tf_bits(k0, k1, jb);
        uint32_t b1 = tf_bits(k0, k1, jb + 1u);
        uint32_t b2 = tf_bits(k0, k1, jb + 2u);
        V3 incA = { bits_to_inc(a0, C, c), bits_to_inc(a1, C, c), bits_to_inc(a2, C, c) };
        V3 incB = { bits_to_inc(b0, C, c), bits_to_inc(b1, C, c), bits_to_inc(b2, C, c) };
        heun_step(A, incA);
        heun_step(B, incB);
    }

    float* oa = out + 3u * g;
    float* ob = out + 3u * (g + nhalf);
    oa[0] = A.x; oa[1] = A.y; oa[2] = A.z;
    ob[0] = B.x; ob[1] = B.y; ob[2] = B.z;
}

extern "C" void kernel_launch(void* const* d_in, const int* in_sizes, int n_in,
                              void* d_out, int out_size, void* d_ws, size_t ws_size,
                              hipStream_t stream) {
    const float* x      = (const float*)d_in[0];
    const int*   t_ptr  = (const int*)d_in[1];
    const int*   steps  = (const int*)d_in[2];
    float*       out    = (float*)d_out;

    const uint32_t npts  = (uint32_t)(in_sizes[0] / 3);    // 4194304 points
    const uint32_t nhalf = npts / 2;                       // 2097152 threads
    const uint32_t grid  = (nhalf + BLOCK - 1) / BLOCK;    // 8192 blocks

    sbm_kernel<<<grid, BLOCK, 0, stream>>>(x, t_ptr, steps, out, nhalf);
}